// Round 1
// baseline (138.273 us; speedup 1.0000x reference)
//
#include <hip/hip_runtime.h>

#define BIG 1e8f
#define LN2 0.69314718f
#define LOG2E 1.44269504f
#define M2L -2.8853900818f  /* -2*log2(e) */

#define RSLOT 112           /* band ring slots (anti-diagonal rows) */
#define DRB 1040            /* drow stride bytes: 256 cols * 4B(half2) + 16 pad */

/* dynamic LDS layout */
#define OFF_XH   116480     /* band: [0, 116480) = 112*1040 */
#define OFF_X2S  132864     /* xh: 16384 B f16 */
#define OFF_Y2S  133888
#define OFF_RDY  134912     /* 16 ready flags */
#define OFF_PRG  134976     /* consumer progress */
#define LDS_BYTES 135040

typedef _Float16 half8 __attribute__((ext_vector_type(8)));
typedef _Float16 half2_t __attribute__((ext_vector_type(2)));
typedef float f32x4 __attribute__((ext_vector_type(4)));

__device__ __forceinline__ float exp2g(float x) {
#if __has_builtin(__builtin_amdgcn_exp2f)
    return __builtin_amdgcn_exp2f(x);
#else
    return exp2f(x);
#endif
}
__device__ __forceinline__ float log2g(float x) {
#if __has_builtin(__builtin_amdgcn_logf)
    return __builtin_amdgcn_logf(x);
#else
    return log2f(x);
#endif
}

// pack two f32 to f16x2 (v_cvt_pkrtz_f16_f32)
__device__ __forceinline__ half2_t pkrtz(float a, float b) {
    return __builtin_bit_cast(half2_t, __builtin_amdgcn_cvt_pkrtz(a, b));
}

// ---- exponential-pair algebra: value v is carried as (M, S), v = M - log2(S)
// (equivalently 2^-v = 2^-M * S, S >= ~1). The M-chain is fmin+add only; the
// exp2 hangs OFF the chain and feeds the S-chain (one fma behind). log2 is
// only needed to collapse back to a scalar, off the critical path.

// merge two pairs: 2^-Mo*So = 2^-Ma*Sa + 2^-Mb*Sb
__device__ __forceinline__ void pmerge(float Ma, float Sa, float Mb, float Sb,
                                       float& Mo, float& So) {
    const float d = Ma - Mb;
    const float e = exp2g(-fabsf(d));
    Mo = fminf(Ma, Mb);
    So = (d <= 0.f) ? fmaf(Sb, e, Sa) : fmaf(Sa, e, Sb);
}

// scalar-scalar pair build (both S==1): M=min(a,b), S = 1 + 2^-|a-b|
__device__ __forceinline__ void pairp2(float a, float b, float& Mo, float& So) {
    Mo = fminf(a, b);
    So = exp2g(-fabsf(a - b)) + 1.f;
}

// DP cell: out = d + softmin{ pair(Mm,Sm) [up+diag], v=(Mv,Sv) [left] },
// kept in pair form: Mo = d + min(Mm,Mv); 2^-(Mo-d)*So = 2^-Mm*Sm + 2^-Mv*Sv
__device__ __forceinline__ void pcell(float Mm, float Sm, float Mv, float Sv,
                                      float dd, float& Mo, float& So) {
    const float dlt = Mv - Mm;
    const float e = exp2g(-fabsf(dlt));
    const float mu = fminf(Mm, Mv);
    So = (dlt >= 0.f) ? fmaf(Sv, e, Sm) : fmaf(Sm, e, Sv);
    Mo = dd + mu;
}

// whole-wave shift-up-by-1 via DPP wave_shr:1; lane 0 receives oldv.
__device__ __forceinline__ float shfl_up1(float v, float oldv) {
    int r = __builtin_amdgcn_update_dpp(
        __builtin_bit_cast(int, oldv), __builtin_bit_cast(int, v),
        0x138 /*wave_shr:1*/, 0xf, 0xf, false);
    return __builtin_bit_cast(float, r);
}

__device__ __forceinline__ void dec2(unsigned int w, float& a, float& b) {
    half2_t h = __builtin_bit_cast(half2_t, w);
    a = (float)h[0];
    b = (float)h[1];
}

// One block = one batch, 2 waves on 2 SIMDs.
// Wave 1 (producer): MFMA-computes dist*log2(e) as f16 (dA,dB) pairs into an
//   anti-diagonal-major LDS ring. Unchanged from previous version.
// Wave 0 (consumer): R4-verified DP wavefront, but all DP values now carried
//   in exponential-pair (M,S) form so the cell-to-cell dependency chain is
//   fmin+fma instead of sub->exp2->sel->log2->sub. log2 collapse only at row
//   commit (4/superstep) and final output.
__global__ __launch_bounds__(128, 1) void sdtw_kernel(
    const float* __restrict__ x, const float* __restrict__ y,
    float* __restrict__ out) {
    extern __shared__ __align__(16) char smem[];
    unsigned char* band = (unsigned char*)smem;
    _Float16* xh = (_Float16*)(smem + OFF_XH);
    float* x2sL = (float*)(smem + OFF_X2S);   // row norms * log2(e)
    float* y2sL = (float*)(smem + OFF_Y2S);
    volatile int* rdy = (volatile int*)(smem + OFF_RDY);
    volatile int* prg = (volatile int*)(smem + OFF_PRG);

    const int tid = threadIdx.x;  // 0..127
    const int b = blockIdx.x;
    const float* xb = x + (size_t)b * 8192;
    const float* yb = y + (size_t)b * 8192;

    // ---- phase 0 (both waves): stage x as f16 + scaled norms; flags ----
#pragma unroll
    for (int rr = 0; rr < 2; rr++) {
        const int r = tid + rr * 128;
        const float4* px = (const float4*)(xb + r * 32);
        union { _Float16 h[32]; half8 v[4]; } uc;
        float s2 = 0.f;
#pragma unroll
        for (int q = 0; q < 8; q++) {
            float4 f = px[q];
            s2 += f.x * f.x + f.y * f.y + f.z * f.z + f.w * f.w;
            uc.h[4 * q + 0] = (_Float16)f.x;
            uc.h[4 * q + 1] = (_Float16)f.y;
            uc.h[4 * q + 2] = (_Float16)f.z;
            uc.h[4 * q + 3] = (_Float16)f.w;
        }
        half8* dst = (half8*)&xh[r * 32];
#pragma unroll
        for (int q = 0; q < 4; q++) dst[q] = uc.v[q];
        x2sL[r] = s2 * LOG2E;

        const float4* py = (const float4*)(yb + r * 32);
        float t2 = 0.f;
#pragma unroll
        for (int q = 0; q < 8; q++) {
            float4 f = py[q];
            t2 += f.x * f.x + f.y * f.y + f.z * f.z + f.w * f.w;
        }
        y2sL[r] = t2 * LOG2E;
    }
    if (tid < 16) rdy[tid] = 0;
    if (tid == 16) *prg = 0;
    __syncthreads();

    if (tid >= 64) {
        // ================= producer wave =================
        const int lane = tid - 64;
        const int qd = lane >> 4, xr = lane & 15;

        half8 yfrag[16];  // B-frags: lane holds y[ci*16+xr][qd*8+j]
        float yvL[16];
#pragma unroll
        for (int ci = 0; ci < 16; ci++) {
            const float* yp = yb + (ci * 16 + xr) * 32 + qd * 8;
            float4 f0 = *(const float4*)yp;
            float4 f1 = *(const float4*)(yp + 4);
            half8 v;
            v[0] = (_Float16)f0.x; v[1] = (_Float16)f0.y;
            v[2] = (_Float16)f0.z; v[3] = (_Float16)f0.w;
            v[4] = (_Float16)f1.x; v[5] = (_Float16)f1.y;
            v[6] = (_Float16)f1.z; v[7] = (_Float16)f1.w;
            yfrag[ci] = v;
            yvL[ci] = y2sL[ci * 16 + xr];
        }

        for (int sg = 0; sg < 16; sg++) {
            // ring-reuse gate: stripe sg touches drows [8sg, 8sg+70]; the
            // aliased drows (d-112) need consumer progress >= 8sg-40.
            if (sg >= 6) {
                const int need = 8 * sg - 40;
                while (*prg < need) {}
            }
            const half8 xf = *(const half8*)&xh[(sg * 16 + xr) * 32 + qd * 8];
            const float4 xl = *(const float4*)&x2sL[sg * 16 + qd * 4];
            const int p0 = 8 * sg + 2 * qd;  // global pair of acc[0],acc[1]
#pragma unroll
            for (int ci = 0; ci < 16; ci++) {
                f32x4 acc = {0.f, 0.f, 0.f, 0.f};
                acc = __builtin_amdgcn_mfma_f32_16x16x32_f16(xf, yfrag[ci], acc, 0, 0, 0);
                const int c = ci * 16 + xr;
                const float yv = yvL[ci];
                const float d0 = fmaxf(fmaf(M2L, acc[0], xl.x + yv), 0.f);
                const float d1 = fmaxf(fmaf(M2L, acc[1], xl.y + yv), 0.f);
                const float d2 = fmaxf(fmaf(M2L, acc[2], xl.z + yv), 0.f);
                const float d3 = fmaxf(fmaf(M2L, acc[3], xl.w + yv), 0.f);
                const half2_t h01 = pkrtz(d0, d1);
                const half2_t h23 = pkrtz(d2, d3);
                const int dr0 = p0 + (c >> 2);          // anti-diagonal row
                int s0_ = dr0;     if (s0_ >= RSLOT) s0_ -= RSLOT;
                int s1_ = dr0 + 1; if (s1_ >= RSLOT) s1_ -= RSLOT;
                *(half2_t*)&band[s0_ * DRB + 4 * c] = h01;
                *(half2_t*)&band[s1_ * DRB + 4 * c] = h23;
            }
            __threadfence_block();  // drain LDS writes before flagging
            if (lane == 0) rdy[sg] = 1;
        }
        return;
    }

    // ================= consumer (DP) wave =================
    const int lane = tid;
    // committed previous-B-row values, collapsed scalars (only ever used to
    // build next-row softmin pairs + final output)
    float aU0 = BIG, aU1 = BIG, aU2 = BIG, aU3 = BIG;
    // relay state in pair form
    float MpA3 = BIG, SpA3 = 1.f, MpB3 = BIG, SpB3 = 1.f;
    float MG0 = (lane == 0) ? 0.f : BIG, SG0 = 1.f;
    // A-row softmin pairs (up,diag) for the upcoming superstep
    float Mm0, Sm0, Mm1, Sm1, Mm2, Sm2, Mm3, Sm3;
    pmerge(aU0, 1.f, MG0, SG0, Mm0, Sm0);
    pairp2(aU1, aU0, Mm1, Sm1);
    pairp2(aU2, aU1, Mm2, Sm2);
    pairp2(aU3, aU2, Mm3, Sm3);

    while (rdy[0] == 0) {}
    uint4 wreg = *(const uint4*)&band[16 * lane];  // drow 0

    for (int s_ = 1; s_ <= 191; s_++) {
        // chain head: pure-VALU cross-lane relay (pairs)
        const float MLA = shfl_up1(MpA3, BIG);  // D[rA][c-1]
        const float SLA = shfl_up1(SpA3, 1.f);
        const float MLB = shfl_up1(MpB3, BIG);  // D[rB][c-1]
        const float SLB = shfl_up1(SpB3, 1.f);

        float dA0, dB0, dA1, dB1, dA2, dB2, dA3, dB3;
        dec2(wreg.x, dA0, dB0);
        dec2(wreg.y, dA1, dB1);
        dec2(wreg.z, dA2, dB2);
        dec2(wreg.w, dA3, dB3);

        // A-row chain: M-chain is fmin+add per cell; exp2 off-path feeds S
        float MA0, SA0, MA1, SA1, MA2, SA2, MA3, SA3;
        pcell(Mm0, Sm0, MLA, SLA, dA0, MA0, SA0);
        pcell(Mm1, Sm1, MA0, SA0, dA1, MA1, SA1);
        pcell(Mm2, Sm2, MA1, SA1, dA2, MA2, SA2);
        pcell(Mm3, Sm3, MA2, SA2, dA3, MA3, SA3);

        // once per 8 supersteps: stripe-ready poll + progress publish
        if ((s_ & 7) == 0) {
            int st = s_ >> 3;
            if (st > 15) st = 15;
            while (rdy[st] == 0) {}
            if (lane == 0) *prg = s_;
        }
        // prefetch next drow (= s_), used next superstep
        int dn = (s_ > 190) ? 190 : s_;
        if (dn >= RSLOT) dn -= RSLOT;
        const uint4 wnext = *(const uint4*)&band[dn * DRB + 16 * lane];

        // B-row pairs: pair-pair merges (up=A_k, diag=A_{k-1}/L0)
        float Mn0, Sn0, Mn1, Sn1, Mn2, Sn2, Mn3, Sn3;
        pmerge(MA0, SA0, MLA, SLA, Mn0, Sn0);
        pmerge(MA1, SA1, MA0, SA0, Mn1, Sn1);
        pmerge(MA2, SA2, MA1, SA1, Mn2, Sn2);
        pmerge(MA3, SA3, MA2, SA2, Mn3, Sn3);
        float MB0, SB0, MB1, SB1, MB2, SB2, MB3, SB3;
        pcell(Mn0, Sn0, MLB, SLB, dB0, MB0, SB0);
        pcell(Mn1, Sn1, MB0, SB0, dB1, MB1, SB1);
        pcell(Mn2, Sn2, MB1, SB1, dB2, MB2, SB2);
        pcell(Mn3, Sn3, MB2, SB2, dB3, MB3, SB3);

        // collapse B-row to scalars (log2 off the recurrence path; a full
        // superstep of slack before these feed next-row pairs)
        const float aB0 = MB0 - log2g(SB0);
        const float aB1 = MB1 - log2g(SB1);
        const float aB2 = MB2 - log2g(SB2);
        const float aB3 = MB3 - log2g(SB3);

        // commit (lane active iff pair p = s_-lane-1 in [0,127])
        const bool act = (unsigned)(s_ - lane - 1) < 128u;
        aU0 = act ? aB0 : aU0;
        aU1 = act ? aB1 : aU1;
        aU2 = act ? aB2 : aU2;
        aU3 = act ? aB3 : aU3;
        MpA3 = act ? MA3 : MpA3; SpA3 = act ? SA3 : SpA3;
        MpB3 = act ? MB3 : MpB3; SpB3 = act ? SB3 : SpB3;
        MG0 = MLB; SG0 = SLB;   // diag(s+1) = D[rB(s)][c-1], kept as pair
        pmerge(aU0, 1.f, MG0, SG0, Mm0, Sm0);
        pairp2(aU1, aU0, Mm1, Sm1);
        pairp2(aU2, aU1, Mm2, Sm2);
        pairp2(aU3, aU2, Mm3, Sm3);
        wreg = wnext;
    }

    if (lane == 63) atomicAdd(out, aU3 * (LN2 / 256.f));  // D[256][256] -> mean
}

extern "C" void kernel_launch(void* const* d_in, const int* in_sizes, int n_in,
                              void* d_out, int out_size, void* d_ws, size_t ws_size,
                              hipStream_t stream) {
    const float* x = (const float*)d_in[0];
    const float* y = (const float*)d_in[1];
    float* out = (float*)d_out;
    const int B = in_sizes[0] / (256 * 32);  // 256

    (void)hipFuncSetAttribute((const void*)sdtw_kernel,
                              hipFuncAttributeMaxDynamicSharedMemorySize,
                              LDS_BYTES);
    (void)hipMemsetAsync(d_out, 0, sizeof(float), stream);
    sdtw_kernel<<<dim3(B), dim3(128), LDS_BYTES, stream>>>(x, y, out);
}

// Round 2
// 137.104 us; speedup vs baseline: 1.0085x; 1.0085x over previous
//
#include <hip/hip_runtime.h>

#define BIG 1e8f
#define LN2 0.69314718f
#define LOG2E 1.44269504f
#define M2L -2.8853900818f  /* -2*log2(e) */

#define RSLOT 112           /* band ring slots (anti-diagonal rows) */
#define DRB 1040            /* drow stride bytes: 256 cols * 4B(half2) + 16 pad */

/* dynamic LDS layout */
#define OFF_XH   116480     /* band: [0, 116480) = 112*1040 */
#define OFF_X2S  132864     /* xh: 16384 B f16 */
#define OFF_Y2S  133888
#define OFF_RDY  134912     /* 16 ready flags */
#define OFF_PRG  134976     /* consumer progress */
#define LDS_BYTES 135040

typedef _Float16 half8 __attribute__((ext_vector_type(8)));
typedef _Float16 half2_t __attribute__((ext_vector_type(2)));
typedef float f32x4 __attribute__((ext_vector_type(4)));

__device__ __forceinline__ float exp2g(float x) {
#if __has_builtin(__builtin_amdgcn_exp2f)
    return __builtin_amdgcn_exp2f(x);
#else
    return exp2f(x);
#endif
}
__device__ __forceinline__ float log2g(float x) {
#if __has_builtin(__builtin_amdgcn_logf)
    return __builtin_amdgcn_logf(x);
#else
    return log2f(x);
#endif
}

// pack two f32 to f16x2 (v_cvt_pkrtz_f16_f32)
__device__ __forceinline__ half2_t pkrtz(float a, float b) {
    return __builtin_bit_cast(half2_t, __builtin_amdgcn_cvt_pkrtz(a, b));
}

// ---- exponential-pair algebra: value v carried as (M, S), v = M - log2(S)
// (2^-v = 2^-M * S). M-chain per merge is fmin(+add); the exp2 hangs OFF the
// chain feeding the S-chain one fma behind. NO log2 anywhere in the loop —
// committed row values stay in pair form; one log2 at final output.

// merge two pairs: 2^-Mo*So = 2^-Ma*Sa + 2^-Mb*Sb
__device__ __forceinline__ void pmerge(float Ma, float Sa, float Mb, float Sb,
                                       float& Mo, float& So) {
    const float d = Ma - Mb;
    const float e = exp2g(-fabsf(d));
    Mo = fminf(Ma, Mb);
    So = (d <= 0.f) ? fmaf(Sb, e, Sa) : fmaf(Sa, e, Sb);
}

// DP cell: out = d + softmin{ pair(Mm,Sm) [up+diag], pair(Mv,Sv) [left] }
__device__ __forceinline__ void pcell(float Mm, float Sm, float Mv, float Sv,
                                      float dd, float& Mo, float& So) {
    const float dlt = Mv - Mm;
    const float e = exp2g(-fabsf(dlt));
    const float mu = fminf(Mm, Mv);
    So = (dlt >= 0.f) ? fmaf(Sv, e, Sm) : fmaf(Sm, e, Sv);
    Mo = dd + mu;
}

// whole-wave shift-up-by-1 via DPP wave_shr:1; lane 0 receives oldv.
__device__ __forceinline__ float shfl_up1(float v, float oldv) {
    int r = __builtin_amdgcn_update_dpp(
        __builtin_bit_cast(int, oldv), __builtin_bit_cast(int, v),
        0x138 /*wave_shr:1*/, 0xf, 0xf, false);
    return __builtin_bit_cast(float, r);
}

__device__ __forceinline__ void dec2(unsigned int w, float& a, float& b) {
    half2_t h = __builtin_bit_cast(half2_t, w);
    a = (float)h[0];
    b = (float)h[1];
}

// One block = one batch, 2 waves on 2 SIMDs.
// Wave 1 (producer): MFMA-computes dist*log2(e) as f16 (dA,dB) pairs into an
//   anti-diagonal-major LDS ring. Unchanged.
// Wave 0 (consumer): DP wavefront in exponential-pair form. Supersteps are
//   unrolled 8-per-group with the ready-poll/progress-publish hoisted to the
//   group head, so the scheduler gets a branch-free ~8-superstep window to
//   interleave independent ops into the serial spine (single-wave latency
//   hiding). Committed rows stay as (M,S) pairs: zero log2 in the loop.
__global__ __launch_bounds__(128, 1) void sdtw_kernel(
    const float* __restrict__ x, const float* __restrict__ y,
    float* __restrict__ out) {
    extern __shared__ __align__(16) char smem[];
    unsigned char* band = (unsigned char*)smem;
    _Float16* xh = (_Float16*)(smem + OFF_XH);
    float* x2sL = (float*)(smem + OFF_X2S);   // row norms * log2(e)
    float* y2sL = (float*)(smem + OFF_Y2S);
    volatile int* rdy = (volatile int*)(smem + OFF_RDY);
    volatile int* prg = (volatile int*)(smem + OFF_PRG);

    const int tid = threadIdx.x;  // 0..127
    const int b = blockIdx.x;
    const float* xb = x + (size_t)b * 8192;
    const float* yb = y + (size_t)b * 8192;

    // ---- phase 0 (both waves): stage x as f16 + scaled norms; flags ----
#pragma unroll
    for (int rr = 0; rr < 2; rr++) {
        const int r = tid + rr * 128;
        const float4* px = (const float4*)(xb + r * 32);
        union { _Float16 h[32]; half8 v[4]; } uc;
        float s2 = 0.f;
#pragma unroll
        for (int q = 0; q < 8; q++) {
            float4 f = px[q];
            s2 += f.x * f.x + f.y * f.y + f.z * f.z + f.w * f.w;
            uc.h[4 * q + 0] = (_Float16)f.x;
            uc.h[4 * q + 1] = (_Float16)f.y;
            uc.h[4 * q + 2] = (_Float16)f.z;
            uc.h[4 * q + 3] = (_Float16)f.w;
        }
        half8* dst = (half8*)&xh[r * 32];
#pragma unroll
        for (int q = 0; q < 4; q++) dst[q] = uc.v[q];
        x2sL[r] = s2 * LOG2E;

        const float4* py = (const float4*)(yb + r * 32);
        float t2 = 0.f;
#pragma unroll
        for (int q = 0; q < 8; q++) {
            float4 f = py[q];
            t2 += f.x * f.x + f.y * f.y + f.z * f.z + f.w * f.w;
        }
        y2sL[r] = t2 * LOG2E;
    }
    if (tid < 16) rdy[tid] = 0;
    if (tid == 16) *prg = 0;
    __syncthreads();

    if (tid >= 64) {
        // ================= producer wave =================
        const int lane = tid - 64;
        const int qd = lane >> 4, xr = lane & 15;

        half8 yfrag[16];  // B-frags: lane holds y[ci*16+xr][qd*8+j]
        float yvL[16];
#pragma unroll
        for (int ci = 0; ci < 16; ci++) {
            const float* yp = yb + (ci * 16 + xr) * 32 + qd * 8;
            float4 f0 = *(const float4*)yp;
            float4 f1 = *(const float4*)(yp + 4);
            half8 v;
            v[0] = (_Float16)f0.x; v[1] = (_Float16)f0.y;
            v[2] = (_Float16)f0.z; v[3] = (_Float16)f0.w;
            v[4] = (_Float16)f1.x; v[5] = (_Float16)f1.y;
            v[6] = (_Float16)f1.z; v[7] = (_Float16)f1.w;
            yfrag[ci] = v;
            yvL[ci] = y2sL[ci * 16 + xr];
        }

        for (int sg = 0; sg < 16; sg++) {
            // ring-reuse gate: stripe sg touches drows [8sg, 8sg+70]; the
            // aliased drows (d-112) need consumer progress >= 8sg-40.
            if (sg >= 6) {
                const int need = 8 * sg - 40;
                while (*prg < need) {}
            }
            const half8 xf = *(const half8*)&xh[(sg * 16 + xr) * 32 + qd * 8];
            const float4 xl = *(const float4*)&x2sL[sg * 16 + qd * 4];
            const int p0 = 8 * sg + 2 * qd;  // global pair of acc[0],acc[1]
#pragma unroll
            for (int ci = 0; ci < 16; ci++) {
                f32x4 acc = {0.f, 0.f, 0.f, 0.f};
                acc = __builtin_amdgcn_mfma_f32_16x16x32_f16(xf, yfrag[ci], acc, 0, 0, 0);
                const int c = ci * 16 + xr;
                const float yv = yvL[ci];
                const float d0 = fmaxf(fmaf(M2L, acc[0], xl.x + yv), 0.f);
                const float d1 = fmaxf(fmaf(M2L, acc[1], xl.y + yv), 0.f);
                const float d2 = fmaxf(fmaf(M2L, acc[2], xl.z + yv), 0.f);
                const float d3 = fmaxf(fmaf(M2L, acc[3], xl.w + yv), 0.f);
                const half2_t h01 = pkrtz(d0, d1);
                const half2_t h23 = pkrtz(d2, d3);
                const int dr0 = p0 + (c >> 2);          // anti-diagonal row
                int s0_ = dr0;     if (s0_ >= RSLOT) s0_ -= RSLOT;
                int s1_ = dr0 + 1; if (s1_ >= RSLOT) s1_ -= RSLOT;
                *(half2_t*)&band[s0_ * DRB + 4 * c] = h01;
                *(half2_t*)&band[s1_ * DRB + 4 * c] = h23;
            }
            __threadfence_block();  // drain LDS writes before flagging
            if (lane == 0) rdy[sg] = 1;
        }
        return;
    }

    // ================= consumer (DP) wave =================
    const int lane = tid;
    // committed previous-B-row values, kept in PAIR form (never collapsed)
    float MU0 = BIG, SU0 = 1.f, MU1 = BIG, SU1 = 1.f;
    float MU2 = BIG, SU2 = 1.f, MU3 = BIG, SU3 = 1.f;
    // relay state in pair form
    float MpA3 = BIG, SpA3 = 1.f, MpB3 = BIG, SpB3 = 1.f;
    float MG0 = (lane == 0) ? 0.f : BIG, SG0 = 1.f;
    // A-row softmin pairs (up,diag) for the upcoming superstep
    float Mm0, Sm0, Mm1, Sm1, Mm2, Sm2, Mm3, Sm3;
    pmerge(MU0, SU0, MG0, SG0, Mm0, Sm0);
    pmerge(MU1, SU1, MU0, SU0, Mm1, Sm1);
    pmerge(MU2, SU2, MU1, SU1, Mm2, Sm2);
    pmerge(MU3, SU3, MU2, SU2, Mm3, Sm3);

    while (rdy[0] == 0) {}
    uint4 wreg = *(const uint4*)&band[16 * lane];  // drow 0

    auto step = [&](int s_) {
        // chain head: pure-VALU cross-lane relay (pairs)
        const float MLA = shfl_up1(MpA3, BIG);  // D[rA][c-1]
        const float SLA = shfl_up1(SpA3, 1.f);
        const float MLB = shfl_up1(MpB3, BIG);  // D[rB][c-1]
        const float SLB = shfl_up1(SpB3, 1.f);

        float dA0, dB0, dA1, dB1, dA2, dB2, dA3, dB3;
        dec2(wreg.x, dA0, dB0);
        dec2(wreg.y, dA1, dB1);
        dec2(wreg.z, dA2, dB2);
        dec2(wreg.w, dA3, dB3);

        // A-row chain: M-chain is fmin+add per cell; exp2 off-path feeds S
        float MA0, SA0, MA1, SA1, MA2, SA2, MA3, SA3;
        pcell(Mm0, Sm0, MLA, SLA, dA0, MA0, SA0);
        pcell(Mm1, Sm1, MA0, SA0, dA1, MA1, SA1);
        pcell(Mm2, Sm2, MA1, SA1, dA2, MA2, SA2);
        pcell(Mm3, Sm3, MA2, SA2, dA3, MA3, SA3);

        // prefetch next drow (= s_), used next superstep
        int dn = (s_ > 190) ? 190 : s_;
        if (dn >= RSLOT) dn -= RSLOT;
        const uint4 wnext = *(const uint4*)&band[dn * DRB + 16 * lane];

        // B-row pairs: pair-pair merges (up=A_k, diag=A_{k-1}/relay)
        float Mn0, Sn0, Mn1, Sn1, Mn2, Sn2, Mn3, Sn3;
        pmerge(MA0, SA0, MLA, SLA, Mn0, Sn0);
        pmerge(MA1, SA1, MA0, SA0, Mn1, Sn1);
        pmerge(MA2, SA2, MA1, SA1, Mn2, Sn2);
        pmerge(MA3, SA3, MA2, SA2, Mn3, Sn3);
        float MB0, SB0, MB1, SB1, MB2, SB2, MB3, SB3;
        pcell(Mn0, Sn0, MLB, SLB, dB0, MB0, SB0);
        pcell(Mn1, Sn1, MB0, SB0, dB1, MB1, SB1);
        pcell(Mn2, Sn2, MB1, SB1, dB2, MB2, SB2);
        pcell(Mn3, Sn3, MB2, SB2, dB3, MB3, SB3);

        // commit (lane active iff pair p = s_-lane-1 in [0,127]); committed
        // values STAY in pair form — no log2 anywhere in the loop.
        const bool act = (unsigned)(s_ - lane - 1) < 128u;
        MU0 = act ? MB0 : MU0; SU0 = act ? SB0 : SU0;
        MU1 = act ? MB1 : MU1; SU1 = act ? SB1 : SU1;
        MU2 = act ? MB2 : MU2; SU2 = act ? SB2 : SU2;
        MU3 = act ? MB3 : MU3; SU3 = act ? SB3 : SU3;
        MpA3 = act ? MA3 : MpA3; SpA3 = act ? SA3 : SpA3;
        MpB3 = act ? MB3 : MpB3; SpB3 = act ? SB3 : SpB3;
        MG0 = MLB; SG0 = SLB;   // diag(s+1) = D[rB(s)][c-1], kept as pair
        pmerge(MU0, SU0, MG0, SG0, Mm0, Sm0);
        pmerge(MU1, SU1, MU0, SU0, Mm1, Sm1);
        pmerge(MU2, SU2, MU1, SU1, Mm2, Sm2);
        pmerge(MU3, SU3, MU2, SU2, Mm3, Sm3);
        wreg = wnext;
    };

    // prologue: supersteps 1..7 (stripe 0 covers drows 0..7)
#pragma unroll
    for (int s_ = 1; s_ < 8; s_++) step(s_);

    // 23 groups of 8 supersteps, poll/publish hoisted to group head
    for (int g = 1; g < 24; g++) {
        int st = (g > 15) ? 15 : g;
        while (rdy[st] == 0) {}
        if (lane == 0) *prg = 8 * g;
        const int s0 = 8 * g;
#pragma unroll
        for (int k = 0; k < 8; k++) step(s0 + k);
    }

    if (lane == 63)  // D[256][256] -> mean; single log2 collapse at the end
        atomicAdd(out, (MU3 - log2g(SU3)) * (LN2 / 256.f));
}

extern "C" void kernel_launch(void* const* d_in, const int* in_sizes, int n_in,
                              void* d_out, int out_size, void* d_ws, size_t ws_size,
                              hipStream_t stream) {
    const float* x = (const float*)d_in[0];
    const float* y = (const float*)d_in[1];
    float* out = (float*)d_out;
    const int B = in_sizes[0] / (256 * 32);  // 256

    (void)hipFuncSetAttribute((const void*)sdtw_kernel,
                              hipFuncAttributeMaxDynamicSharedMemorySize,
                              LDS_BYTES);
    (void)hipMemsetAsync(d_out, 0, sizeof(float), stream);
    sdtw_kernel<<<dim3(B), dim3(128), LDS_BYTES, stream>>>(x, y, out);
}

// Round 3
// 129.979 us; speedup vs baseline: 1.0638x; 1.0548x over previous
//
#include <hip/hip_runtime.h>

#define BIG 1e8f
#define LN2 0.69314718f
#define LOG2E 1.44269504f
#define M2L -2.8853900818f  /* -2*log2(e) */

#define RSLOT 112           /* band ring slots (anti-diagonal rows) */
#define DRB 1040            /* drow stride bytes: 256 cols * 4B(half2) + 16 pad */

/* dynamic LDS layout */
#define OFF_XH   116480     /* band: [0, 116480) = 112*1040 */
#define OFF_X2S  132864     /* xh: 16384 B f16 */
#define OFF_Y2S  133888
#define OFF_RDY  134912     /* 16 ready flags */
#define OFF_PRG  134976     /* consumer progress */
#define LDS_BYTES 135040

typedef _Float16 half8 __attribute__((ext_vector_type(8)));
typedef _Float16 half2_t __attribute__((ext_vector_type(2)));
typedef float f32x4 __attribute__((ext_vector_type(4)));

__device__ __forceinline__ float exp2g(float x) {
#if __has_builtin(__builtin_amdgcn_exp2f)
    return __builtin_amdgcn_exp2f(x);
#else
    return exp2f(x);
#endif
}
__device__ __forceinline__ float log2g(float x) {
#if __has_builtin(__builtin_amdgcn_logf)
    return __builtin_amdgcn_logf(x);
#else
    return log2f(x);
#endif
}

// pack two f32 to f16x2 (v_cvt_pkrtz_f16_f32)
__device__ __forceinline__ half2_t pkrtz(float a, float b) {
    return __builtin_bit_cast(half2_t, __builtin_amdgcn_cvt_pkrtz(a, b));
}

// ---- exponential-pair algebra: value v carried as (M, S), v = M - log2(S)
// (2^-v = 2^-M * S). M-chain per merge is fmin(+add); the exp2 hangs OFF the
// chain feeding the S-chain one fma behind. NO log2 in the loop.

// merge two pairs: 2^-Mo*So = 2^-Ma*Sa + 2^-Mb*Sb
__device__ __forceinline__ void pmerge(float Ma, float Sa, float Mb, float Sb,
                                       float& Mo, float& So) {
    const float d = Ma - Mb;
    const float e = exp2g(-fabsf(d));
    Mo = fminf(Ma, Mb);
    So = (d <= 0.f) ? fmaf(Sb, e, Sa) : fmaf(Sa, e, Sb);
}

// DP cell: out = d + softmin{ pair(Mm,Sm) [up+diag], pair(Mv,Sv) [left] }
__device__ __forceinline__ void pcell(float Mm, float Sm, float Mv, float Sv,
                                      float dd, float& Mo, float& So) {
    const float dlt = Mv - Mm;
    const float e = exp2g(-fabsf(dlt));
    const float mu = fminf(Mm, Mv);
    So = (dlt >= 0.f) ? fmaf(Sv, e, Sm) : fmaf(Sm, e, Sv);
    Mo = dd + mu;
}

// whole-wave shift-up-by-1 via DPP wave_shr:1; lane 0 receives oldv.
__device__ __forceinline__ float shfl_up1(float v, float oldv) {
    int r = __builtin_amdgcn_update_dpp(
        __builtin_bit_cast(int, oldv), __builtin_bit_cast(int, v),
        0x138 /*wave_shr:1*/, 0xf, 0xf, false);
    return __builtin_bit_cast(float, r);
}

__device__ __forceinline__ void dec2(unsigned int w, float& a, float& b) {
    half2_t h = __builtin_bit_cast(half2_t, w);
    a = (float)h[0];
    b = (float)h[1];
}

// Inactive-lane word masks: per-column-DISTINCT huge f16 values. An inactive
// lane computes unconditionally; its state walks ~1e8 + t*c_k which is
// softmin-exact no-op vs real values (e flushes to 0), and distinct c_k keep
// pre-window merge deltas huge so S never compounds. This replaces the
// 12-cndmask commit with 4 word-cndmasks (issue-bound loop: fewer instrs).
#define MASKW0 0x7BFF7BFFu  /* 65504 */
#define MASKW1 0x70007000u  /* 8192  */
#define MASKW2 0x60006000u  /* 512   */
#define MASKW3 0x50005000u  /* 32    */

// One block = one batch, 2 waves on 2 SIMDs.
// Wave 1 (producer): MFMA-computes dist*log2(e) as f16 (dA,dB) pairs into an
//   anti-diagonal-major LDS ring. Unchanged.
// Wave 0 (consumer): DP wavefront in exponential-pair form; unconditional
//   commits via input-masking (above); drow prefetch hoisted right after
//   decode for max LDS-latency cover.
__global__ __launch_bounds__(128, 1) void sdtw_kernel(
    const float* __restrict__ x, const float* __restrict__ y,
    float* __restrict__ out) {
    extern __shared__ __align__(16) char smem[];
    unsigned char* band = (unsigned char*)smem;
    _Float16* xh = (_Float16*)(smem + OFF_XH);
    float* x2sL = (float*)(smem + OFF_X2S);   // row norms * log2(e)
    float* y2sL = (float*)(smem + OFF_Y2S);
    volatile int* rdy = (volatile int*)(smem + OFF_RDY);
    volatile int* prg = (volatile int*)(smem + OFF_PRG);

    const int tid = threadIdx.x;  // 0..127
    const int b = blockIdx.x;
    const float* xb = x + (size_t)b * 8192;
    const float* yb = y + (size_t)b * 8192;

    // ---- phase 0 (both waves): stage x as f16 + scaled norms; flags ----
#pragma unroll
    for (int rr = 0; rr < 2; rr++) {
        const int r = tid + rr * 128;
        const float4* px = (const float4*)(xb + r * 32);
        union { _Float16 h[32]; half8 v[4]; } uc;
        float s2 = 0.f;
#pragma unroll
        for (int q = 0; q < 8; q++) {
            float4 f = px[q];
            s2 += f.x * f.x + f.y * f.y + f.z * f.z + f.w * f.w;
            uc.h[4 * q + 0] = (_Float16)f.x;
            uc.h[4 * q + 1] = (_Float16)f.y;
            uc.h[4 * q + 2] = (_Float16)f.z;
            uc.h[4 * q + 3] = (_Float16)f.w;
        }
        half8* dst = (half8*)&xh[r * 32];
#pragma unroll
        for (int q = 0; q < 4; q++) dst[q] = uc.v[q];
        x2sL[r] = s2 * LOG2E;

        const float4* py = (const float4*)(yb + r * 32);
        float t2 = 0.f;
#pragma unroll
        for (int q = 0; q < 8; q++) {
            float4 f = py[q];
            t2 += f.x * f.x + f.y * f.y + f.z * f.z + f.w * f.w;
        }
        y2sL[r] = t2 * LOG2E;
    }
    if (tid < 16) rdy[tid] = 0;
    if (tid == 16) *prg = 0;
    __syncthreads();

    if (tid >= 64) {
        // ================= producer wave =================
        const int lane = tid - 64;
        const int qd = lane >> 4, xr = lane & 15;

        half8 yfrag[16];  // B-frags: lane holds y[ci*16+xr][qd*8+j]
        float yvL[16];
#pragma unroll
        for (int ci = 0; ci < 16; ci++) {
            const float* yp = yb + (ci * 16 + xr) * 32 + qd * 8;
            float4 f0 = *(const float4*)yp;
            float4 f1 = *(const float4*)(yp + 4);
            half8 v;
            v[0] = (_Float16)f0.x; v[1] = (_Float16)f0.y;
            v[2] = (_Float16)f0.z; v[3] = (_Float16)f0.w;
            v[4] = (_Float16)f1.x; v[5] = (_Float16)f1.y;
            v[6] = (_Float16)f1.z; v[7] = (_Float16)f1.w;
            yfrag[ci] = v;
            yvL[ci] = y2sL[ci * 16 + xr];
        }

        for (int sg = 0; sg < 16; sg++) {
            // ring-reuse gate: stripe sg touches drows [8sg, 8sg+70]; the
            // aliased drows (d-112) need consumer progress >= 8sg-40.
            if (sg >= 6) {
                const int need = 8 * sg - 40;
                while (*prg < need) {}
            }
            const half8 xf = *(const half8*)&xh[(sg * 16 + xr) * 32 + qd * 8];
            const float4 xl = *(const float4*)&x2sL[sg * 16 + qd * 4];
            const int p0 = 8 * sg + 2 * qd;  // global pair of acc[0],acc[1]
#pragma unroll
            for (int ci = 0; ci < 16; ci++) {
                f32x4 acc = {0.f, 0.f, 0.f, 0.f};
                acc = __builtin_amdgcn_mfma_f32_16x16x32_f16(xf, yfrag[ci], acc, 0, 0, 0);
                const int c = ci * 16 + xr;
                const float yv = yvL[ci];
                const float d0 = fmaxf(fmaf(M2L, acc[0], xl.x + yv), 0.f);
                const float d1 = fmaxf(fmaf(M2L, acc[1], xl.y + yv), 0.f);
                const float d2 = fmaxf(fmaf(M2L, acc[2], xl.z + yv), 0.f);
                const float d3 = fmaxf(fmaf(M2L, acc[3], xl.w + yv), 0.f);
                const half2_t h01 = pkrtz(d0, d1);
                const half2_t h23 = pkrtz(d2, d3);
                const int dr0 = p0 + (c >> 2);          // anti-diagonal row
                int s0_ = dr0;     if (s0_ >= RSLOT) s0_ -= RSLOT;
                int s1_ = dr0 + 1; if (s1_ >= RSLOT) s1_ -= RSLOT;
                *(half2_t*)&band[s0_ * DRB + 4 * c] = h01;
                *(half2_t*)&band[s1_ * DRB + 4 * c] = h23;
            }
            __threadfence_block();  // drain LDS writes before flagging
            if (lane == 0) rdy[sg] = 1;
        }
        return;
    }

    // ================= consumer (DP) wave =================
    const int lane = tid;
    // relay state in pair form (unconditional commits; masking is on inputs)
    float MpA3 = BIG, SpA3 = 1.f, MpB3 = BIG, SpB3 = 1.f;
    float MG0 = (lane == 0) ? 0.f : BIG, SG0 = 1.f;
    // A-row softmin pairs (up,diag) for the upcoming superstep
    float Mm0, Sm0, Mm1, Sm1, Mm2, Sm2, Mm3, Sm3;
    pmerge(BIG, 1.f, MG0, SG0, Mm0, Sm0);
    pmerge(BIG, 1.f, BIG, 1.f, Mm1, Sm1);
    Mm2 = Mm1; Sm2 = Sm1;
    Mm3 = Mm1; Sm3 = Sm1;

    while (rdy[0] == 0) {}
    uint4 wreg = *(const uint4*)&band[16 * lane];  // drow 0

    auto step = [&](int s_) {
        // chain head: pure-VALU cross-lane relay (pairs)
        const float MLA = shfl_up1(MpA3, BIG);  // D[rA][c-1]
        const float SLA = shfl_up1(SpA3, 1.f);
        const float MLB = shfl_up1(MpB3, BIG);  // D[rB][c-1]
        const float SLB = shfl_up1(SpB3, 1.f);

        // input masking: inactive lanes get huge, per-column-distinct d's
        const bool act = (unsigned)(s_ - lane - 1) < 128u;
        const unsigned wx = act ? wreg.x : MASKW0;
        const unsigned wy = act ? wreg.y : MASKW1;
        const unsigned wz = act ? wreg.z : MASKW2;
        const unsigned ww = act ? wreg.w : MASKW3;
        float dA0, dB0, dA1, dB1, dA2, dB2, dA3, dB3;
        dec2(wx, dA0, dB0);
        dec2(wy, dA1, dB1);
        dec2(wz, dA2, dB2);
        dec2(ww, dA3, dB3);

        // prefetch next drow (= s_), used next superstep — issued early
        int dn = (s_ > 190) ? 190 : s_;
        if (dn >= RSLOT) dn -= RSLOT;
        const uint4 wnext = *(const uint4*)&band[dn * DRB + 16 * lane];

        // A-row chain: M-chain is fmin+add per cell; exp2 off-path feeds S
        float MA0, SA0, MA1, SA1, MA2, SA2, MA3, SA3;
        pcell(Mm0, Sm0, MLA, SLA, dA0, MA0, SA0);
        pcell(Mm1, Sm1, MA0, SA0, dA1, MA1, SA1);
        pcell(Mm2, Sm2, MA1, SA1, dA2, MA2, SA2);
        pcell(Mm3, Sm3, MA2, SA2, dA3, MA3, SA3);

        // B-row pairs: pair-pair merges (up=A_k, diag=A_{k-1}/relay)
        float Mn0, Sn0, Mn1, Sn1, Mn2, Sn2, Mn3, Sn3;
        pmerge(MA0, SA0, MLA, SLA, Mn0, Sn0);
        pmerge(MA1, SA1, MA0, SA0, Mn1, Sn1);
        pmerge(MA2, SA2, MA1, SA1, Mn2, Sn2);
        pmerge(MA3, SA3, MA2, SA2, Mn3, Sn3);
        float MB0, SB0, MB1, SB1, MB2, SB2, MB3, SB3;
        pcell(Mn0, Sn0, MLB, SLB, dB0, MB0, SB0);
        pcell(Mn1, Sn1, MB0, SB0, dB1, MB1, SB1);
        pcell(Mn2, Sn2, MB1, SB1, dB2, MB2, SB2);
        pcell(Mn3, Sn3, MB2, SB2, dB3, MB3, SB3);

        // UNCONDITIONAL commit (input masking makes inactive lanes no-ops)
        MpA3 = MA3; SpA3 = SA3;
        MpB3 = MB3; SpB3 = SB3;
        MG0 = MLB; SG0 = SLB;   // diag(s+1) = D[rB(s)][c-1], kept as pair
        pmerge(MB0, SB0, MG0, SG0, Mm0, Sm0);
        pmerge(MB1, SB1, MB0, SB0, Mm1, Sm1);
        pmerge(MB2, SB2, MB1, SB1, Mm2, Sm2);
        pmerge(MB3, SB3, MB2, SB2, Mm3, Sm3);
        wreg = wnext;
    };

    // prologue: supersteps 1..7 (stripe 0 covers drows 0..7)
#pragma unroll
    for (int s_ = 1; s_ < 8; s_++) step(s_);

    // 23 groups of 8 supersteps, poll/publish hoisted to group head
    for (int g = 1; g < 24; g++) {
        int st = (g > 15) ? 15 : g;
        while (rdy[st] == 0) {}
        if (lane == 0) *prg = 8 * g;
        const int s0 = 8 * g;
#pragma unroll
        for (int k = 0; k < 8; k++) step(s0 + k);
    }

    // lane 63's superstep-191 commit is the final cell D[256][256]
    if (lane == 63)
        atomicAdd(out, (MpB3 - log2g(SpB3)) * (LN2 / 256.f));
}

extern "C" void kernel_launch(void* const* d_in, const int* in_sizes, int n_in,
                              void* d_out, int out_size, void* d_ws, size_t ws_size,
                              hipStream_t stream) {
    const float* x = (const float*)d_in[0];
    const float* y = (const float*)d_in[1];
    float* out = (float*)d_out;
    const int B = in_sizes[0] / (256 * 32);  // 256

    (void)hipFuncSetAttribute((const void*)sdtw_kernel,
                              hipFuncAttributeMaxDynamicSharedMemorySize,
                              LDS_BYTES);
    (void)hipMemsetAsync(d_out, 0, sizeof(float), stream);
    sdtw_kernel<<<dim3(B), dim3(128), LDS_BYTES, stream>>>(x, y, out);
}